// Round 27
// baseline (1290.389 us; speedup 1.0000x reference)
//
#include <hip/hip_runtime.h>
#include <math.h>

// Swin-3D basic layer, bf16-MFMA: [QKV+LN1] [attn] [proj+LN2] [FC1+gelu] [FC2+res]
// Round 27: odd-dword LDS strides — K192 weight tiles 200->202 u16 (101 dwords),
// fc2 tiles 72->74 u16 (37 dwords). Old strides were ≡4 (mod 32) dwords ->
// bank = 4(i+g): 8-way conflicts (fc1 4.7M, fc2 5.5M per dispatch). New ≡5 ->
// bank = 5i+4g: <=2-way (free). Layout fixed at wtrans/h_t build time (DMA linear).

#define L_TOK 131072
#define C_DIM 192
#define NWIN 2048

// padded strides (u16)
#define WS192 202          // K=192 weight row stride; chunk = 64*202 = 12928
#define WCH   12928
#define WCHP  13312        // chunk + 384 tail (26 KB DMA target)
#define FS    74           // fc2 tile row stride; f2w chunk = 192*74 = 14208
#define FCH   14208
#define FCHP  14336        // + 128 tail (28 KB DMA target)

typedef unsigned int uint32;
typedef unsigned short u16;
typedef __bf16 bf16x8 __attribute__((ext_vector_type(8)));
typedef __bf16 bf16x4 __attribute__((ext_vector_type(4)));
typedef float f32x4 __attribute__((ext_vector_type(4)));

__device__ __forceinline__ u16 f2bf(float f) {
    uint32 u = __float_as_uint(f);
    u += 0x7fffu + ((u >> 16) & 1u);
    return (u16)(u >> 16);
}
__device__ __forceinline__ float bf2f(u16 h) { return __uint_as_float(((uint32)h) << 16); }

// gelu, tanh/sigmoid form: x * sigma(1.5957691(x + 0.044715x^3)). HW rcp.
__device__ __forceinline__ float gelu_f(float x) {
    const float x2 = x * x;
    const float inner = x * fmaf(0.044715f, x2, 1.0f);
    const float e = __expf(-1.5957691216057308f * inner);
    return x * __builtin_amdgcn_rcpf(1.0f + e);
}

// window-ordered row r -> natural token index (rolled[g] = orig[(g+shift)%D])
__device__ __forceinline__ int win_row_to_token(int r, int shifted) {
    const int win = r >> 6, n = r & 63;
    const int sb = win >> 8, hb = (win >> 4) & 15, wb = win & 15;
    int gz = sb * 4 + (n >> 4);
    int gy = hb * 4 + ((n >> 2) & 3);
    int gx = wb * 4 + (n & 3);
    if (shifted) { gz = (gz + 2) & 31; gy = (gy + 2) & 63; gx = (gx + 2) & 63; }
    return (gz << 12) | (gy << 6) | gx;
}

// direct global->LDS 16B copy (per-lane gsrc, wave-uniform LDS base + lane*16)
__device__ __forceinline__ void gll16(const u16* g, u16* l) {
    __builtin_amdgcn_global_load_lds((const __attribute__((address_space(1))) void*)g,
                                     (__attribute__((address_space(3))) void*)l, 16, 0, 0);
}

// K192 weight chunk: 26 x 1KB wave-calls (25856B data + tail), 4 waves
__device__ __forceinline__ void stage_wchunk4(const u16* __restrict__ gsrc, u16* lds) {
    const int wave = threadIdx.x >> 6, lane = threadIdx.x & 63;
    for (int c = wave; c < 26; c += 4)
        gll16(gsrc + c * 512 + lane * 8, lds + c * 512);
}

// f2w chunk: 28 x 1KB wave-calls (28416B data + tail), 8 waves
__device__ __forceinline__ void stage_wchunk8(const u16* __restrict__ gsrc, u16* lds) {
    const int wave = threadIdx.x >> 6, lane = threadIdx.x & 63;
    for (int c = wave; c < 28; c += 8)
        gll16(gsrc + c * 512 + lane * 8, lds + c * 512);
}

// h chunk: 256*74 u16 = 37888B = 37 x 1KB exactly, 8 waves
__device__ __forceinline__ void stage_hchunk8(const u16* __restrict__ gsrc, u16* lds) {
    const int wave = threadIdx.x >> 6, lane = threadIdx.x & 63;
    for (int c = wave; c < 37; c += 8)
        gll16(gsrc + c * 512 + lane * 8, lds + c * 512);
}

// ---------------------------------------------------------------------------
// merged weight transpose + bf16 convert into PADDED LDS-image layouts:
// mode 0: in [192][N] fp32 -> out[n*202 + k]   (rows 202 u16, contiguous chunks)
// mode 1: in [768][192] fp32 -> out[(k>>6)*14208 + n*74 + (k&63)]
// ---------------------------------------------------------------------------
struct WtSeg { const float* in; u16* out; int N; int nelem; int mode; };
struct WtTable { WtSeg s[8]; };

__global__ __launch_bounds__(256) void wtrans_all_kernel(WtTable t) {
    int idx = blockIdx.x * 256 + threadIdx.x;
#pragma unroll
    for (int si = 0; si < 8; ++si) {
        const WtSeg& sg = t.s[si];
        if (idx < sg.nelem) {
            if (sg.mode == 0) {
                const int n = idx / 192, k = idx - n * 192;
                const int ch = n >> 6, nl = n & 63;
                sg.out[(size_t)ch * WCH + nl * WS192 + k] = f2bf(sg.in[(size_t)k * sg.N + n]);
            } else {
                const int n = idx / 768, k = idx - n * 768;
                sg.out[(k >> 6) * FCH + n * FS + (k & 63)] = f2bf(sg.in[(size_t)k * 192 + n]);
            }
            return;
        }
        idx -= sg.nelem;
    }
}

// rpb [343][6] fp32 -> rpbT [6][343] fp32
__global__ __launch_bounds__(256) void rpbt_kernel(const float* __restrict__ r0,
                                                   const float* __restrict__ r1,
                                                   float* __restrict__ o0,
                                                   float* __restrict__ o1) {
    const int idx = blockIdx.x * 256 + threadIdx.x;
    if (idx < 343 * 6) {
        const int h = idx / 343, r = idx - h * 343;
        o0[idx] = r0[r * 6 + h];
        o1[idx] = r1[r * 6 + h];
    }
}

__device__ __forceinline__ void load_tok_regs(const u16* __restrict__ base, bf16x8 (&xb)[2][6]) {
    const int lane = threadIdx.x & 63, wave = threadIdx.x >> 6;
    const int i = lane & 15, g = lane >> 4;
#pragma unroll
    for (int tt = 0; tt < 2; ++tt)
#pragma unroll
        for (int ks = 0; ks < 6; ++ks)
            xb[tt][ks] = *(const bf16x8*)(base + (size_t)(32 * wave + 16 * tt + i) * 192 +
                                          32 * ks + 8 * g);
}

// ---------------------------------------------------------------------------
// QKV + fused LN1 (256 threads, M=128): weight chunks via global_load_lds.
// ---------------------------------------------------------------------------
__global__ __launch_bounds__(256) void qkv_ln_mfma(const float* __restrict__ X,
                                                   const float* __restrict__ g1,
                                                   const float* __restrict__ b1,
                                                   const u16* __restrict__ qwT,
                                                   const float* __restrict__ qb,
                                                   u16* __restrict__ q, u16* __restrict__ k,
                                                   u16* __restrict__ v, int shifted) {
    __shared__ __align__(16) u16 Bs[2][WCHP];
    const int m0 = blockIdx.x * 128;
    const int lane = threadIdx.x & 63, wave = threadIdx.x >> 6;
    const int i = lane & 15, g = lane >> 4;

    stage_wchunk4(qwT, Bs[0]);

    bf16x8 xb[2][6];
#pragma unroll
    for (int tt = 0; tt < 2; ++tt) {
        const int m = m0 + 32 * wave + 16 * tt + i;
        const int t = win_row_to_token(m, shifted);
        const float* xr = X + (size_t)t * C_DIM;
        float vv[6][8];
        float s = 0.0f;
#pragma unroll
        for (int ks = 0; ks < 6; ++ks) {
            const float4 a = *(const float4*)(xr + 32 * ks + 8 * g);
            const float4 b = *(const float4*)(xr + 32 * ks + 8 * g + 4);
            vv[ks][0] = a.x; vv[ks][1] = a.y; vv[ks][2] = a.z; vv[ks][3] = a.w;
            vv[ks][4] = b.x; vv[ks][5] = b.y; vv[ks][6] = b.z; vv[ks][7] = b.w;
            s += a.x + a.y + a.z + a.w + b.x + b.y + b.z + b.w;
        }
        s += __shfl_xor(s, 16, 64);
        s += __shfl_xor(s, 32, 64);
        const float mu = s * (1.0f / 192.0f);
        float sq = 0.0f;
#pragma unroll
        for (int ks = 0; ks < 6; ++ks)
#pragma unroll
            for (int j = 0; j < 8; ++j) {
                const float d = vv[ks][j] - mu;
                sq += d * d;
            }
        sq += __shfl_xor(sq, 16, 64);
        sq += __shfl_xor(sq, 32, 64);
        const float rstd = rsqrtf(sq * (1.0f / 192.0f) + 1e-5f);
#pragma unroll
        for (int ks = 0; ks < 6; ++ks) {
            const int c0 = 32 * ks + 8 * g;
            const float4 ga = *(const float4*)(g1 + c0);
            const float4 gb = *(const float4*)(g1 + c0 + 4);
            const float4 ba = *(const float4*)(b1 + c0);
            const float4 bb = *(const float4*)(b1 + c0 + 4);
            u16 tmp[8];
            tmp[0] = f2bf((vv[ks][0] - mu) * rstd * ga.x + ba.x);
            tmp[1] = f2bf((vv[ks][1] - mu) * rstd * ga.y + ba.y);
            tmp[2] = f2bf((vv[ks][2] - mu) * rstd * ga.z + ba.z);
            tmp[3] = f2bf((vv[ks][3] - mu) * rstd * ga.w + ba.w);
            tmp[4] = f2bf((vv[ks][4] - mu) * rstd * gb.x + bb.x);
            tmp[5] = f2bf((vv[ks][5] - mu) * rstd * gb.y + bb.y);
            tmp[6] = f2bf((vv[ks][6] - mu) * rstd * gb.z + bb.z);
            tmp[7] = f2bf((vv[ks][7] - mu) * rstd * gb.w + bb.w);
            xb[tt][ks] = *(const bf16x8*)tmp;
        }
    }

    __syncthreads();
#pragma unroll 1
    for (int nc = 0; nc < 9; ++nc) {
        const int cur = nc & 1;
        if (nc < 8) stage_wchunk4(qwT + (size_t)(nc + 1) * WCH, Bs[cur ^ 1]);
        f32x4 acc[4][2] = {};
        const u16* paw = Bs[cur] + i * WS192 + 8 * g;
#pragma unroll
        for (int ks = 0; ks < 6; ++ks) {
#pragma unroll
            for (int a = 0; a < 4; ++a) {
                const bf16x8 av = *(const bf16x8*)(paw + a * 16 * WS192 + ks * 32);
                acc[a][0] = __builtin_amdgcn_mfma_f32_16x16x32_bf16(av, xb[0][ks], acc[a][0], 0, 0, 0);
                acc[a][1] = __builtin_amdgcn_mfma_f32_16x16x32_bf16(av, xb[1][ks], acc[a][1], 0, 0, 0);
            }
        }
        const int which = nc / 3;
        u16* dst = (which == 0) ? q : (which == 1) ? k : v;
        const float sc = (which == 0) ? 0.17677669529663687f : 1.0f;
#pragma unroll
        for (int a = 0; a < 4; ++a) {
            const int n0 = nc * 64 + 16 * a + 4 * g;
            const int hn = n0 - which * 192;
            const int head = hn >> 5, hd0 = hn & 31;
            const float4 bi = *(const float4*)(qb + n0);
#pragma unroll
            for (int tt = 0; tt < 2; ++tt) {
                const int m = m0 + wave * 32 + 16 * tt + i;
                const int win = m >> 6, tok = m & 63;
                ushort4 pk;
                pk.x = f2bf((acc[a][tt][0] + bi.x) * sc);
                pk.y = f2bf((acc[a][tt][1] + bi.y) * sc);
                pk.z = f2bf((acc[a][tt][2] + bi.z) * sc);
                pk.w = f2bf((acc[a][tt][3] + bi.w) * sc);
                *(ushort4*)(dst + ((size_t)(win * 6 + head) * 64 + tok) * 32 + hd0) = pk;
            }
        }
        __syncthreads();
    }
}

// ---------------------------------------------------------------------------
// MFMA attention (256 threads, 1 window, rpbT bias, setprio, pre-normalized P).
// ---------------------------------------------------------------------------
__global__ __launch_bounds__(256) void attn_mfma(const u16* __restrict__ qg,
                                                 const u16* __restrict__ kg,
                                                 const u16* __restrict__ vg,
                                                 const float* __restrict__ rpbT,
                                                 u16* __restrict__ o, int shifted) {
    __shared__ __align__(16) u16 vt[32 * 68];
    __shared__ __align__(16) u16 ps[64 * 68];
    __shared__ __align__(16) u16 os[64 * 40];
    __shared__ float bias_s[343];
    __shared__ int ms[64];
    const int tid = threadIdx.x;
    const int lane = tid & 63, w = tid >> 6;
    const int i = lane & 15, g = lane >> 4;
    const int head = blockIdx.x >> 11;
    const int win = blockIdx.x & 2047;
    const size_t base = (size_t)(win * 6 + head) * 2048;

    const bf16x8 qf = *(const bf16x8*)(qg + base + (size_t)(16 * w + i) * 32 + 8 * g);
    bf16x8 kf[4];
#pragma unroll
    for (int t = 0; t < 4; ++t)
        kf[t] = *(const bf16x8*)(kg + base + (size_t)(16 * t + i) * 32 + 8 * g);
    {
        const int n = tid >> 2, c0 = (tid & 3) * 8;
        uint4 raw = *(const uint4*)(vg + base + (size_t)n * 32 + c0);
        const u16* pr = (const u16*)&raw;
#pragma unroll
        for (int j = 0; j < 8; ++j) vt[(c0 + j) * 68 + n] = pr[j];
    }
    for (int idx = tid; idx < 343; idx += 256) bias_s[idx] = rpbT[head * 343 + idx];
    if (tid < 64) {
        int mv = 0;
        if (shifted) {
            const int sb = win >> 8, hb = (win >> 4) & 15, wb = win & 15;
            const int gz = sb * 4 + (tid >> 4);
            const int gy = hb * 4 + ((tid >> 2) & 3);
            const int gx = wb * 4 + (tid & 3);
            const int rz = gz < 28 ? 0 : (gz < 30 ? 1 : 2);
            const int ry = gy < 60 ? 0 : (gy < 62 ? 1 : 2);
            const int rw = gx < 60 ? 0 : (gx < 62 ? 1 : 2);
            mv = rz * 9 + ry * 3 + rw;
        }
        ms[tid] = mv;
    }
    __syncthreads();

    __builtin_amdgcn_s_setprio(1);
    const f32x4 zero = {0.0f, 0.0f, 0.0f, 0.0f};
    f32x4 s[4];
#pragma unroll
    for (int t = 0; t < 4; ++t)
        s[t] = __builtin_amdgcn_mfma_f32_16x16x32_bf16(kf[t], qf, zero, 0, 0, 0);

    const int qrow = 16 * w + i;
    const int mq = ms[qrow];
    float p[16];
#pragma unroll
    for (int t = 0; t < 4; ++t)
#pragma unroll
        for (int r = 0; r < 4; ++r) {
            const int j = 16 * t + 4 * g + r;
            const int dz = (qrow >> 4) - (j >> 4) + 3;
            const int dy = ((qrow >> 2) & 3) - ((j >> 2) & 3) + 3;
            const int dx = (qrow & 3) - (j & 3) + 3;
            float val = s[t][r] + bias_s[dz * 49 + dy * 7 + dx];
            if (shifted && (mq != ms[j])) val -= 100.0f;
            p[t * 4 + r] = val;
        }
    float mx = -3.0e38f;
#pragma unroll
    for (int u = 0; u < 16; ++u) mx = fmaxf(mx, p[u]);
    mx = fmaxf(mx, __shfl_xor(mx, 16, 64));
    mx = fmaxf(mx, __shfl_xor(mx, 32, 64));
    float sum = 0.0f;
#pragma unroll
    for (int u = 0; u < 16; ++u) { p[u] = __expf(p[u] - mx); sum += p[u]; }
    sum += __shfl_xor(sum, 16, 64);
    sum += __shfl_xor(sum, 32, 64);
    const float inv = __builtin_amdgcn_rcpf(sum);

#pragma unroll
    for (int t = 0; t < 4; ++t) {
        ushort4 pk;
        pk.x = f2bf(p[t * 4 + 0] * inv); pk.y = f2bf(p[t * 4 + 1] * inv);
        pk.z = f2bf(p[t * 4 + 2] * inv); pk.w = f2bf(p[t * 4 + 3] * inv);
        *(ushort4*)(ps + (size_t)qrow * 68 + 16 * t + 4 * g) = pk;
    }

    f32x4 oacc[2] = {zero, zero};
#pragma unroll
    for (int kb = 0; kb < 2; ++kb) {
        const bf16x4 alo = *(const bf16x4*)(ps + (size_t)qrow * 68 + 8 * g + 32 * kb);
        const bf16x4 ahi = *(const bf16x4*)(ps + (size_t)qrow * 68 + 8 * g + 32 * kb + 4);
        const bf16x8 a = __builtin_shufflevector(alo, ahi, 0, 1, 2, 3, 4, 5, 6, 7);
#pragma unroll
        for (int ct = 0; ct < 2; ++ct) {
            const bf16x4 blo = *(const bf16x4*)(vt + (size_t)(i + 16 * ct) * 68 + 8 * g + 32 * kb);
            const bf16x4 bhi = *(const bf16x4*)(vt + (size_t)(i + 16 * ct) * 68 + 8 * g + 32 * kb + 4);
            const bf16x8 b = __builtin_shufflevector(blo, bhi, 0, 1, 2, 3, 4, 5, 6, 7);
            oacc[ct] = __builtin_amdgcn_mfma_f32_16x16x32_bf16(a, b, oacc[ct], 0, 0, 0);
        }
    }
    __builtin_amdgcn_s_setprio(0);
#pragma unroll
    for (int ct = 0; ct < 2; ++ct)
#pragma unroll
        for (int r = 0; r < 4; ++r)
            os[(16 * w + 4 * g + r) * 40 + i + 16 * ct] = f2bf(oacc[ct][r]);
    __syncthreads();
    {
        const int n = tid >> 2, c0 = (tid & 3) * 8;
        const uint4 val = *(const uint4*)(os + n * 40 + c0);
        *(uint4*)(o + (size_t)(win * 64 + n) * C_DIM + head * 32 + c0) = val;
    }
}

// ---------------------------------------------------------------------------
// proj + residual + LN2 fused: o rows in regs, weight chunks via global_load_lds.
// ---------------------------------------------------------------------------
__global__ __launch_bounds__(256) void proj_ln_mfma(const u16* __restrict__ o,
                                                    const u16* __restrict__ pwT,
                                                    const float* __restrict__ pb,
                                                    const float* xin,
                                                    const float* __restrict__ g2,
                                                    const float* __restrict__ b2,
                                                    float* x2, u16* __restrict__ x2n,
                                                    int shifted) {
    __shared__ __align__(16) u16 Bs[2][WCHP];
    const int m0 = blockIdx.x * 128;
    const int lane = threadIdx.x & 63, wave = threadIdx.x >> 6;
    const int i = lane & 15, g = lane >> 4;
    stage_wchunk4(pwT, Bs[0]);
    bf16x8 xb[2][6];
    load_tok_regs(o + (size_t)m0 * 192, xb);
    __syncthreads();
    f32x4 acc[12][2] = {};
#pragma unroll
    for (int nc = 0; nc < 3; ++nc) {
        const int cur = nc & 1;
        if (nc < 2) stage_wchunk4(pwT + (size_t)(nc + 1) * WCH, Bs[cur ^ 1]);
        const u16* paw = Bs[cur] + i * WS192 + 8 * g;
#pragma unroll
        for (int ks = 0; ks < 6; ++ks) {
#pragma unroll
            for (int a = 0; a < 4; ++a) {
                const bf16x8 av = *(const bf16x8*)(paw + a * 16 * WS192 + ks * 32);
                acc[nc * 4 + a][0] = __builtin_amdgcn_mfma_f32_16x16x32_bf16(av, xb[0][ks], acc[nc * 4 + a][0], 0, 0, 0);
                acc[nc * 4 + a][1] = __builtin_amdgcn_mfma_f32_16x16x32_bf16(av, xb[1][ks], acc[nc * 4 + a][1], 0, 0, 0);
            }
        }
        __syncthreads();
    }
#pragma unroll
    for (int tt = 0; tt < 2; ++tt) {
        const int m = m0 + wave * 32 + 16 * tt + i;
        const int t = win_row_to_token(m, shifted);
        const float* xr = xin + (size_t)t * C_DIM;
        float s = 0.0f;
#pragma unroll
        for (int a = 0; a < 12; ++a) {
            const int n0 = 16 * a + 4 * g;
            const float4 xv = *(const float4*)(xr + n0);
            const float4 bi = *(const float4*)(pb + n0);
            acc[a][tt][0] += xv.x + bi.x;
            acc[a][tt][1] += xv.y + bi.y;
            acc[a][tt][2] += xv.z + bi.z;
            acc[a][tt][3] += xv.w + bi.w;
            s += acc[a][tt][0] + acc[a][tt][1] + acc[a][tt][2] + acc[a][tt][3];
        }
        s += __shfl_xor(s, 16, 64);
        s += __shfl_xor(s, 32, 64);
        const float mu = s * (1.0f / 192.0f);
        float sq = 0.0f;
#pragma unroll
        for (int a = 0; a < 12; ++a) {
#pragma unroll
            for (int r = 0; r < 4; ++r) {
                const float d = acc[a][tt][r] - mu;
                sq += d * d;
            }
        }
        sq += __shfl_xor(sq, 16, 64);
        sq += __shfl_xor(sq, 32, 64);
        const float rstd = rsqrtf(sq * (1.0f / 192.0f) + 1e-5f);
        float* x2r = x2 + (size_t)t * C_DIM;
        u16* xnr = x2n + (size_t)t * C_DIM;
#pragma unroll
        for (int a = 0; a < 12; ++a) {
            const int n0 = 16 * a + 4 * g;
            float4 wv;
            wv.x = acc[a][tt][0]; wv.y = acc[a][tt][1];
            wv.z = acc[a][tt][2]; wv.w = acc[a][tt][3];
            *(float4*)(x2r + n0) = wv;
            const float4 gv = *(const float4*)(g2 + n0);
            const float4 bv = *(const float4*)(b2 + n0);
            ushort4 nk;
            nk.x = f2bf((wv.x - mu) * rstd * gv.x + bv.x);
            nk.y = f2bf((wv.y - mu) * rstd * gv.y + bv.y);
            nk.z = f2bf((wv.z - mu) * rstd * gv.z + bv.z);
            nk.w = f2bf((wv.w - mu) * rstd * gv.w + bv.w);
            *(ushort4*)(xnr + n0) = nk;
        }
    }
}

// ---------------------------------------------------------------------------
// FC1 + gelu: weights via DMA; h written in fc2 tile image h_t[nc][m][74].
// ---------------------------------------------------------------------------
__global__ __launch_bounds__(256) void fc1_mfma(const u16* __restrict__ x2n,
                                                const u16* __restrict__ f1wT,
                                                const float* __restrict__ f1b,
                                                u16* __restrict__ h_t) {
    __shared__ __align__(16) u16 Bs[2][WCHP];
    const int m0 = blockIdx.x * 128;
    const int lane = threadIdx.x & 63, wave = threadIdx.x >> 6;
    const int i = lane & 15, g = lane >> 4;
    stage_wchunk4(f1wT, Bs[0]);
    bf16x8 xb[2][6];
    load_tok_regs(x2n + (size_t)m0 * 192, xb);
    __syncthreads();
#pragma unroll 1
    for (int nc = 0; nc < 12; ++nc) {
        const int cur = nc & 1;
        if (nc < 11) stage_wchunk4(f1wT + (size_t)(nc + 1) * WCH, Bs[cur ^ 1]);
        f32x4 acc[4][2] = {};
        const u16* paw = Bs[cur] + i * WS192 + 8 * g;
#pragma unroll
        for (int ks = 0; ks < 6; ++ks) {
#pragma unroll
            for (int a = 0; a < 4; ++a) {
                const bf16x8 av = *(const bf16x8*)(paw + a * 16 * WS192 + ks * 32);
                acc[a][0] = __builtin_amdgcn_mfma_f32_16x16x32_bf16(av, xb[0][ks], acc[a][0], 0, 0, 0);
                acc[a][1] = __builtin_amdgcn_mfma_f32_16x16x32_bf16(av, xb[1][ks], acc[a][1], 0, 0, 0);
            }
        }
        u16* hchunk = h_t + (size_t)nc * ((size_t)L_TOK * FS);
#pragma unroll
        for (int a = 0; a < 4; ++a) {
            const int c0 = 16 * a + 4 * g;
            const float4 bi = *(const float4*)(f1b + nc * 64 + c0);
#pragma unroll
            for (int tt = 0; tt < 2; ++tt) {
                const int m = m0 + wave * 32 + 16 * tt + i;
                ushort4 pk;
                pk.x = f2bf(gelu_f(acc[a][tt][0] + bi.x));
                pk.y = f2bf(gelu_f(acc[a][tt][1] + bi.y));
                pk.z = f2bf(gelu_f(acc[a][tt][2] + bi.z));
                pk.w = f2bf(gelu_f(acc[a][tt][3] + bi.w));
                *(ushort4*)(hchunk + (size_t)m * FS + c0) = pk;
            }
        }
        __syncthreads();
    }
}

// ---------------------------------------------------------------------------
// FC2 + residual (512 threads, M=256): BOTH tiles via global_load_lds,
// stride-74 conflict-free reads.
// ---------------------------------------------------------------------------
__global__ __launch_bounds__(512) void fc2_mfma(const u16* __restrict__ h_t,
                                                const u16* __restrict__ f2wT,
                                                const float* __restrict__ f2b,
                                                const float* x2, float* out) {
    __shared__ __align__(16) u16 As[256 * FS];
    __shared__ __align__(16) u16 Bs[FCHP];
    const int tid = threadIdx.x, lane = tid & 63, wave = tid >> 6;
    const int i = lane & 15, g = lane >> 4;
    const int m0 = blockIdx.x * 256;
    f32x4 acc[12][2] = {};
#pragma unroll 1
    for (int kc = 0; kc < 12; ++kc) {
        stage_hchunk8(h_t + (size_t)kc * ((size_t)L_TOK * FS) + (size_t)m0 * FS, As);
        stage_wchunk8(f2wT + (size_t)kc * FCH, Bs);
        __syncthreads();
        const u16* pbt = As + (wave * 32 + i) * FS + 8 * g;
        const u16* paw = Bs + i * FS + 8 * g;
#pragma unroll
        for (int ks = 0; ks < 2; ++ks) {
            const bf16x8 b0 = *(const bf16x8*)(pbt + ks * 32);
            const bf16x8 b1 = *(const bf16x8*)(pbt + 16 * FS + ks * 32);
#pragma unroll
            for (int a = 0; a < 12; ++a) {
                const bf16x8 av = *(const bf16x8*)(paw + a * 16 * FS + ks * 32);
                acc[a][0] = __builtin_amdgcn_mfma_f32_16x16x32_bf16(av, b0, acc[a][0], 0, 0, 0);
                acc[a][1] = __builtin_amdgcn_mfma_f32_16x16x32_bf16(av, b1, acc[a][1], 0, 0, 0);
            }
        }
        __syncthreads();
    }
#pragma unroll
    for (int tt = 0; tt < 2; ++tt) {
        const int m = m0 + wave * 32 + 16 * tt + i;
        const float* x2r = x2 + (size_t)m * C_DIM;
        float* orow = out + (size_t)m * C_DIM;
#pragma unroll
        for (int a = 0; a < 12; ++a) {
            const int n0 = 16 * a + 4 * g;
            const float4 xv = *(const float4*)(x2r + n0);
            const float4 bi = *(const float4*)(f2b + n0);
            float4 rr;
            rr.x = xv.x + bi.x + acc[a][tt][0];
            rr.y = xv.y + bi.y + acc[a][tt][1];
            rr.z = xv.z + bi.z + acc[a][tt][2];
            rr.w = xv.w + bi.w + acc[a][tt][3];
            *(float4*)(orow + n0) = rr;
        }
    }
}

// ---------------------------------------------------------------------------
// orchestration. ws (PB = 48MB): [0,PB) o ; [PB,2PB) q ; [2PB,3PB) k ;
// [3PB,4PB) v ; h_t (12*L*74 u16 = 233MB) overlays [PB, ...); x2n [6PB,7PB) ;
// padded weights at 7PB ; rpbT after. x2 = d_out fp32.
// ---------------------------------------------------------------------------
static void run_block(const float* X, float* XOUT,
                      const float* g1, const float* b1, const float* qb,
                      const float* rpbT, const float* pb,
                      const float* g2, const float* b2,
                      const float* f1b, const float* f2b,
                      const u16* qwT, const u16* pwT, const u16* f1wT, const u16* f2wT,
                      int shifted, char* ws, hipStream_t stream) {
    const size_t PB = (size_t)L_TOK * C_DIM * sizeof(u16);  // 48 MB
    u16* o   = (u16*)ws;
    u16* q   = (u16*)(ws + PB);
    u16* k   = (u16*)(ws + 2 * PB);
    u16* v   = (u16*)(ws + 3 * PB);
    u16* h_t = (u16*)(ws + PB);
    u16* x2n = (u16*)(ws + 6 * PB);
    float* x2 = XOUT;

    qkv_ln_mfma<<<L_TOK / 128, 256, 0, stream>>>(X, g1, b1, qwT, qb, q, k, v, shifted);
    attn_mfma<<<NWIN * 6, 256, 0, stream>>>(q, k, v, rpbT, o, shifted);
    proj_ln_mfma<<<L_TOK / 128, 256, 0, stream>>>(o, pwT, pb, X, g2, b2, x2, x2n, shifted);
    fc1_mfma<<<L_TOK / 128, 256, 0, stream>>>(x2n, f1wT, f1b, h_t);
    fc2_mfma<<<L_TOK / 256, 512, 0, stream>>>(h_t, f2wT, f2b, x2, XOUT);
}

extern "C" void kernel_launch(void* const* d_in, const int* in_sizes, int n_in,
                              void* d_out, int out_size, void* d_ws, size_t ws_size,
                              hipStream_t stream) {
    const float* x = (const float*)d_in[0];
    float* out = (float*)d_out;
    char* ws = (char*)d_ws;
    auto in = [&](int i) { return (const float*)d_in[i]; };

    const size_t offW = (size_t)L_TOK * C_DIM * sizeof(u16) * 7;
    u16* wbase = (u16*)(ws + offW);
    // padded sizes (u16), incl. DMA tail pads:
    // qwT 9*12928+384, pwT 3*12928+384, f1wT 12*12928+384, f2wT 12*14208+128
    const size_t SQ = 9 * WCH + 384, SP = 3 * WCH + 384, SF1 = 12 * WCH + 384,
                 SF2 = 12 * FCH + 128;
    const size_t WBLK = SQ + SP + SF1 + SF2;
    u16* qwT[2]  = { wbase,                    wbase + WBLK };
    u16* pwT[2]  = { wbase + SQ,               wbase + WBLK + SQ };
    u16* f1wT[2] = { wbase + SQ + SP,          wbase + WBLK + SQ + SP };
    u16* f2wT[2] = { wbase + SQ + SP + SF1,    wbase + WBLK + SQ + SP + SF1 };
    float* rpbT0 = (float*)(wbase + 2 * WBLK);
    float* rpbT1 = rpbT0 + 6 * 343;

    WtTable wt;
    wt.s[0] = { in(3),  qwT[0],  576, 576 * 192, 0 };
    wt.s[1] = { in(6),  pwT[0],  192, 192 * 192, 0 };
    wt.s[2] = { in(10), f1wT[0], 768, 768 * 192, 0 };
    wt.s[3] = { in(12), f2wT[0], 192, 192 * 768, 1 };
    wt.s[4] = { in(16), qwT[1],  576, 576 * 192, 0 };
    wt.s[5] = { in(19), pwT[1],  192, 192 * 192, 0 };
    wt.s[6] = { in(23), f1wT[1], 768, 768 * 192, 0 };
    wt.s[7] = { in(25), f2wT[1], 192, 192 * 768, 1 };
    int total = 0;
    for (int s = 0; s < 8; ++s) total += wt.s[s].nelem;
    wtrans_all_kernel<<<(total + 255) / 256, 256, 0, stream>>>(wt);
    rpbt_kernel<<<(343 * 6 + 255) / 256, 256, 0, stream>>>(in(5), in(18), rpbT0, rpbT1);

    run_block(x, out, in(1), in(2), in(4), rpbT0, in(7), in(8), in(9), in(11), in(13),
              qwT[0], pwT[0], f1wT[0], f2wT[0], 0, ws, stream);
    run_block(out, out, in(14), in(15), in(17), rpbT1, in(20), in(21), in(22), in(24), in(26),
              qwT[1], pwT[1], f1wT[1], f2wT[1], 1, ws, stream);
}

// Round 28
// 792.149 us; speedup vs baseline: 1.6290x; 1.6290x over previous
//
#include <hip/hip_runtime.h>
#include <math.h>

// Swin-3D basic layer, bf16-MFMA: [QKV+LN1] [attn] [proj+LN2] [FC1+gelu] [FC2+res]
// Round 28: REVERT to r26 (794us best). r27's odd-stride experiment eliminated
// LDS bank conflicts (counter -> 0) but broke ds_read_b128 16B alignment
// (404/148B rows), doubling fc2 — conflicts were NOT critical-path (regime gate
// confirmed); alignment is. Strides back to 200/72.

#define L_TOK 131072
#define C_DIM 192
#define NWIN 2048

typedef unsigned int uint32;
typedef unsigned short u16;
typedef __bf16 bf16x8 __attribute__((ext_vector_type(8)));
typedef __bf16 bf16x4 __attribute__((ext_vector_type(4)));
typedef float f32x4 __attribute__((ext_vector_type(4)));

__device__ __forceinline__ u16 f2bf(float f) {
    uint32 u = __float_as_uint(f);
    u += 0x7fffu + ((u >> 16) & 1u);
    return (u16)(u >> 16);
}
__device__ __forceinline__ float bf2f(u16 h) { return __uint_as_float(((uint32)h) << 16); }

// gelu, tanh/sigmoid form: x * sigma(1.5957691(x + 0.044715x^3)). HW rcp.
__device__ __forceinline__ float gelu_f(float x) {
    const float x2 = x * x;
    const float inner = x * fmaf(0.044715f, x2, 1.0f);
    const float e = __expf(-1.5957691216057308f * inner);
    return x * __builtin_amdgcn_rcpf(1.0f + e);
}

// window-ordered row r -> natural token index (rolled[g] = orig[(g+shift)%D])
__device__ __forceinline__ int win_row_to_token(int r, int shifted) {
    const int win = r >> 6, n = r & 63;
    const int sb = win >> 8, hb = (win >> 4) & 15, wb = win & 15;
    int gz = sb * 4 + (n >> 4);
    int gy = hb * 4 + ((n >> 2) & 3);
    int gx = wb * 4 + (n & 3);
    if (shifted) { gz = (gz + 2) & 31; gy = (gy + 2) & 63; gx = (gx + 2) & 63; }
    return (gz << 12) | (gy << 6) | gx;
}

// direct global->LDS 16B copy (per-lane gsrc, wave-uniform LDS base + lane*16)
__device__ __forceinline__ void gll16(const u16* g, u16* l) {
    __builtin_amdgcn_global_load_lds((const __attribute__((address_space(1))) void*)g,
                                     (__attribute__((address_space(3))) void*)l, 16, 0, 0);
}

__device__ __forceinline__ void stage_wchunk4(const u16* __restrict__ gsrc, u16* lds) {
    const int wave = threadIdx.x >> 6, lane = threadIdx.x & 63;
    for (int c = wave; c < 25; c += 4)
        gll16(gsrc + c * 512 + lane * 8, lds + c * 512);
}

__device__ __forceinline__ void stage_wchunk8(const u16* __restrict__ gsrc, u16* lds) {
    const int wave = threadIdx.x >> 6, lane = threadIdx.x & 63;
    for (int c = wave; c < 27; c += 8)
        gll16(gsrc + c * 512 + lane * 8, lds + c * 512);
}

__device__ __forceinline__ void stage_hchunk8(const u16* __restrict__ gsrc, u16* lds) {
    const int wave = threadIdx.x >> 6, lane = threadIdx.x & 63;
    for (int c = wave; c < 36; c += 8)
        gll16(gsrc + c * 512 + lane * 8, lds + c * 512);
}

// ---------------------------------------------------------------------------
// merged weight transpose + bf16 convert into PADDED LDS-image layouts
// mode 0: in [192][N] fp32 -> out[n*200 + k]; mode 1: f2w tiled [12][192][72]
// ---------------------------------------------------------------------------
struct WtSeg { const float* in; u16* out; int N; int nelem; int mode; };
struct WtTable { WtSeg s[8]; };

__global__ __launch_bounds__(256) void wtrans_all_kernel(WtTable t) {
    int idx = blockIdx.x * 256 + threadIdx.x;
#pragma unroll
    for (int si = 0; si < 8; ++si) {
        const WtSeg& sg = t.s[si];
        if (idx < sg.nelem) {
            if (sg.mode == 0) {
                const int n = idx / 192, k = idx - n * 192;
                sg.out[n * 200 + k] = f2bf(sg.in[(size_t)k * sg.N + n]);
            } else {
                const int n = idx / 768, k = idx - n * 768;
                sg.out[(k >> 6) * 13824 + n * 72 + (k & 63)] = f2bf(sg.in[(size_t)k * 192 + n]);
            }
            return;
        }
        idx -= sg.nelem;
    }
}

// rpb [343][6] fp32 -> rpbT [6][343] fp32
__global__ __launch_bounds__(256) void rpbt_kernel(const float* __restrict__ r0,
                                                   const float* __restrict__ r1,
                                                   float* __restrict__ o0,
                                                   float* __restrict__ o1) {
    const int idx = blockIdx.x * 256 + threadIdx.x;
    if (idx < 343 * 6) {
        const int h = idx / 343, r = idx - h * 343;
        o0[idx] = r0[r * 6 + h];
        o1[idx] = r1[r * 6 + h];
    }
}

__device__ __forceinline__ void load_tok_regs(const u16* __restrict__ base, bf16x8 (&xb)[2][6]) {
    const int lane = threadIdx.x & 63, wave = threadIdx.x >> 6;
    const int i = lane & 15, g = lane >> 4;
#pragma unroll
    for (int tt = 0; tt < 2; ++tt)
#pragma unroll
        for (int ks = 0; ks < 6; ++ks)
            xb[tt][ks] = *(const bf16x8*)(base + (size_t)(32 * wave + 16 * tt + i) * 192 +
                                          32 * ks + 8 * g);
}

// ---------------------------------------------------------------------------
// QKV + fused LN1 (256 threads, M=128): weight chunks via global_load_lds.
// ---------------------------------------------------------------------------
__global__ __launch_bounds__(256) void qkv_ln_mfma(const float* __restrict__ X,
                                                   const float* __restrict__ g1,
                                                   const float* __restrict__ b1,
                                                   const u16* __restrict__ qwT,
                                                   const float* __restrict__ qb,
                                                   u16* __restrict__ q, u16* __restrict__ k,
                                                   u16* __restrict__ v, int shifted) {
    __shared__ __align__(16) u16 Bs[2][64 * 200];
    const int m0 = blockIdx.x * 128;
    const int lane = threadIdx.x & 63, wave = threadIdx.x >> 6;
    const int i = lane & 15, g = lane >> 4;

    stage_wchunk4(qwT, Bs[0]);

    bf16x8 xb[2][6];
#pragma unroll
    for (int tt = 0; tt < 2; ++tt) {
        const int m = m0 + 32 * wave + 16 * tt + i;
        const int t = win_row_to_token(m, shifted);
        const float* xr = X + (size_t)t * C_DIM;
        float vv[6][8];
        float s = 0.0f;
#pragma unroll
        for (int ks = 0; ks < 6; ++ks) {
            const float4 a = *(const float4*)(xr + 32 * ks + 8 * g);
            const float4 b = *(const float4*)(xr + 32 * ks + 8 * g + 4);
            vv[ks][0] = a.x; vv[ks][1] = a.y; vv[ks][2] = a.z; vv[ks][3] = a.w;
            vv[ks][4] = b.x; vv[ks][5] = b.y; vv[ks][6] = b.z; vv[ks][7] = b.w;
            s += a.x + a.y + a.z + a.w + b.x + b.y + b.z + b.w;
        }
        s += __shfl_xor(s, 16, 64);
        s += __shfl_xor(s, 32, 64);
        const float mu = s * (1.0f / 192.0f);
        float sq = 0.0f;
#pragma unroll
        for (int ks = 0; ks < 6; ++ks)
#pragma unroll
            for (int j = 0; j < 8; ++j) {
                const float d = vv[ks][j] - mu;
                sq += d * d;
            }
        sq += __shfl_xor(sq, 16, 64);
        sq += __shfl_xor(sq, 32, 64);
        const float rstd = rsqrtf(sq * (1.0f / 192.0f) + 1e-5f);
#pragma unroll
        for (int ks = 0; ks < 6; ++ks) {
            const int c0 = 32 * ks + 8 * g;
            const float4 ga = *(const float4*)(g1 + c0);
            const float4 gb = *(const float4*)(g1 + c0 + 4);
            const float4 ba = *(const float4*)(b1 + c0);
            const float4 bb = *(const float4*)(b1 + c0 + 4);
            u16 tmp[8];
            tmp[0] = f2bf((vv[ks][0] - mu) * rstd * ga.x + ba.x);
            tmp[1] = f2bf((vv[ks][1] - mu) * rstd * ga.y + ba.y);
            tmp[2] = f2bf((vv[ks][2] - mu) * rstd * ga.z + ba.z);
            tmp[3] = f2bf((vv[ks][3] - mu) * rstd * ga.w + ba.w);
            tmp[4] = f2bf((vv[ks][4] - mu) * rstd * gb.x + bb.x);
            tmp[5] = f2bf((vv[ks][5] - mu) * rstd * gb.y + bb.y);
            tmp[6] = f2bf((vv[ks][6] - mu) * rstd * gb.z + bb.z);
            tmp[7] = f2bf((vv[ks][7] - mu) * rstd * gb.w + bb.w);
            xb[tt][ks] = *(const bf16x8*)tmp;
        }
    }

    __syncthreads();
#pragma unroll 1
    for (int nc = 0; nc < 9; ++nc) {
        const int cur = nc & 1;
        if (nc < 8) stage_wchunk4(qwT + (size_t)(nc + 1) * 12800, Bs[cur ^ 1]);
        f32x4 acc[4][2] = {};
        const u16* paw = Bs[cur] + i * 200 + 8 * g;
#pragma unroll
        for (int ks = 0; ks < 6; ++ks) {
#pragma unroll
            for (int a = 0; a < 4; ++a) {
                const bf16x8 av = *(const bf16x8*)(paw + a * 16 * 200 + ks * 32);
                acc[a][0] = __builtin_amdgcn_mfma_f32_16x16x32_bf16(av, xb[0][ks], acc[a][0], 0, 0, 0);
                acc[a][1] = __builtin_amdgcn_mfma_f32_16x16x32_bf16(av, xb[1][ks], acc[a][1], 0, 0, 0);
            }
        }
        const int which = nc / 3;
        u16* dst = (which == 0) ? q : (which == 1) ? k : v;
        const float sc = (which == 0) ? 0.17677669529663687f : 1.0f;
#pragma unroll
        for (int a = 0; a < 4; ++a) {
            const int n0 = nc * 64 + 16 * a + 4 * g;
            const int hn = n0 - which * 192;
            const int head = hn >> 5, hd0 = hn & 31;
            const float4 bi = *(const float4*)(qb + n0);
#pragma unroll
            for (int tt = 0; tt < 2; ++tt) {
                const int m = m0 + wave * 32 + 16 * tt + i;
                const int win = m >> 6, tok = m & 63;
                ushort4 pk;
                pk.x = f2bf((acc[a][tt][0] + bi.x) * sc);
                pk.y = f2bf((acc[a][tt][1] + bi.y) * sc);
                pk.z = f2bf((acc[a][tt][2] + bi.z) * sc);
                pk.w = f2bf((acc[a][tt][3] + bi.w) * sc);
                *(ushort4*)(dst + ((size_t)(win * 6 + head) * 64 + tok) * 32 + hd0) = pk;
            }
        }
        __syncthreads();
    }
}

// ---------------------------------------------------------------------------
// MFMA attention (256 threads, 1 window, rpbT bias, setprio, pre-normalized P).
// ---------------------------------------------------------------------------
__global__ __launch_bounds__(256) void attn_mfma(const u16* __restrict__ qg,
                                                 const u16* __restrict__ kg,
                                                 const u16* __restrict__ vg,
                                                 const float* __restrict__ rpbT,
                                                 u16* __restrict__ o, int shifted) {
    __shared__ __align__(16) u16 vt[32 * 68];
    __shared__ __align__(16) u16 ps[64 * 68];
    __shared__ __align__(16) u16 os[64 * 40];
    __shared__ float bias_s[343];
    __shared__ int ms[64];
    const int tid = threadIdx.x;
    const int lane = tid & 63, w = tid >> 6;
    const int i = lane & 15, g = lane >> 4;
    const int head = blockIdx.x >> 11;
    const int win = blockIdx.x & 2047;
    const size_t base = (size_t)(win * 6 + head) * 2048;

    const bf16x8 qf = *(const bf16x8*)(qg + base + (size_t)(16 * w + i) * 32 + 8 * g);
    bf16x8 kf[4];
#pragma unroll
    for (int t = 0; t < 4; ++t)
        kf[t] = *(const bf16x8*)(kg + base + (size_t)(16 * t + i) * 32 + 8 * g);
    {
        const int n = tid >> 2, c0 = (tid & 3) * 8;
        uint4 raw = *(const uint4*)(vg + base + (size_t)n * 32 + c0);
        const u16* pr = (const u16*)&raw;
#pragma unroll
        for (int j = 0; j < 8; ++j) vt[(c0 + j) * 68 + n] = pr[j];
    }
    for (int idx = tid; idx < 343; idx += 256) bias_s[idx] = rpbT[head * 343 + idx];
    if (tid < 64) {
        int mv = 0;
        if (shifted) {
            const int sb = win >> 8, hb = (win >> 4) & 15, wb = win & 15;
            const int gz = sb * 4 + (tid >> 4);
            const int gy = hb * 4 + ((tid >> 2) & 3);
            const int gx = wb * 4 + (tid & 3);
            const int rz = gz < 28 ? 0 : (gz < 30 ? 1 : 2);
            const int ry = gy < 60 ? 0 : (gy < 62 ? 1 : 2);
            const int rw = gx < 60 ? 0 : (gx < 62 ? 1 : 2);
            mv = rz * 9 + ry * 3 + rw;
        }
        ms[tid] = mv;
    }
    __syncthreads();

    __builtin_amdgcn_s_setprio(1);
    const f32x4 zero = {0.0f, 0.0f, 0.0f, 0.0f};
    f32x4 s[4];
#pragma unroll
    for (int t = 0; t < 4; ++t)
        s[t] = __builtin_amdgcn_mfma_f32_16x16x32_bf16(kf[t], qf, zero, 0, 0, 0);

    const int qrow = 16 * w + i;
    const int mq = ms[qrow];
    float p[16];
#pragma unroll
    for (int t = 0; t < 4; ++t)
#pragma unroll
        for (int r = 0; r < 4; ++r) {
            const int j = 16 * t + 4 * g + r;
            const int dz = (qrow >> 4) - (j >> 4) + 3;
            const int dy = ((qrow >> 2) & 3) - ((j >> 2) & 3) + 3;
            const int dx = (qrow & 3) - (j & 3) + 3;
            float val = s[t][r] + bias_s[dz * 49 + dy * 7 + dx];
            if (shifted && (mq != ms[j])) val -= 100.0f;
            p[t * 4 + r] = val;
        }
    float mx = -3.0e38f;
#pragma unroll
    for (int u = 0; u < 16; ++u) mx = fmaxf(mx, p[u]);
    mx = fmaxf(mx, __shfl_xor(mx, 16, 64));
    mx = fmaxf(mx, __shfl_xor(mx, 32, 64));
    float sum = 0.0f;
#pragma unroll
    for (int u = 0; u < 16; ++u) { p[u] = __expf(p[u] - mx); sum += p[u]; }
    sum += __shfl_xor(sum, 16, 64);
    sum += __shfl_xor(sum, 32, 64);
    const float inv = __builtin_amdgcn_rcpf(sum);

#pragma unroll
    for (int t = 0; t < 4; ++t) {
        ushort4 pk;
        pk.x = f2bf(p[t * 4 + 0] * inv); pk.y = f2bf(p[t * 4 + 1] * inv);
        pk.z = f2bf(p[t * 4 + 2] * inv); pk.w = f2bf(p[t * 4 + 3] * inv);
        *(ushort4*)(ps + (size_t)qrow * 68 + 16 * t + 4 * g) = pk;
    }

    f32x4 oacc[2] = {zero, zero};
#pragma unroll
    for (int kb = 0; kb < 2; ++kb) {
        const bf16x4 alo = *(const bf16x4*)(ps + (size_t)qrow * 68 + 8 * g + 32 * kb);
        const bf16x4 ahi = *(const bf16x4*)(ps + (size_t)qrow * 68 + 8 * g + 32 * kb + 4);
        const bf16x8 a = __builtin_shufflevector(alo, ahi, 0, 1, 2, 3, 4, 5, 6, 7);
#pragma unroll
        for (int ct = 0; ct < 2; ++ct) {
            const bf16x4 blo = *(const bf16x4*)(vt + (size_t)(i + 16 * ct) * 68 + 8 * g + 32 * kb);
            const bf16x4 bhi = *(const bf16x4*)(vt + (size_t)(i + 16 * ct) * 68 + 8 * g + 32 * kb + 4);
            const bf16x8 b = __builtin_shufflevector(blo, bhi, 0, 1, 2, 3, 4, 5, 6, 7);
            oacc[ct] = __builtin_amdgcn_mfma_f32_16x16x32_bf16(a, b, oacc[ct], 0, 0, 0);
        }
    }
    __builtin_amdgcn_s_setprio(0);
#pragma unroll
    for (int ct = 0; ct < 2; ++ct)
#pragma unroll
        for (int r = 0; r < 4; ++r)
            os[(16 * w + 4 * g + r) * 40 + i + 16 * ct] = f2bf(oacc[ct][r]);
    __syncthreads();
    {
        const int n = tid >> 2, c0 = (tid & 3) * 8;
        const uint4 val = *(const uint4*)(os + n * 40 + c0);
        *(uint4*)(o + (size_t)(win * 64 + n) * C_DIM + head * 32 + c0) = val;
    }
}

// ---------------------------------------------------------------------------
// proj + residual + LN2 fused: o rows in regs, weight chunks via global_load_lds.
// ---------------------------------------------------------------------------
__global__ __launch_bounds__(256) void proj_ln_mfma(const u16* __restrict__ o,
                                                    const u16* __restrict__ pwT,
                                                    const float* __restrict__ pb,
                                                    const float* xin,
                                                    const float* __restrict__ g2,
                                                    const float* __restrict__ b2,
                                                    float* x2, u16* __restrict__ x2n,
                                                    int shifted) {
    __shared__ __align__(16) u16 Bs[2][64 * 200];
    const int m0 = blockIdx.x * 128;
    const int lane = threadIdx.x & 63, wave = threadIdx.x >> 6;
    const int i = lane & 15, g = lane >> 4;
    stage_wchunk4(pwT, Bs[0]);
    bf16x8 xb[2][6];
    load_tok_regs(o + (size_t)m0 * 192, xb);
    __syncthreads();
    f32x4 acc[12][2] = {};
#pragma unroll
    for (int nc = 0; nc < 3; ++nc) {
        const int cur = nc & 1;
        if (nc < 2) stage_wchunk4(pwT + (size_t)(nc + 1) * 12800, Bs[cur ^ 1]);
        const u16* paw = Bs[cur] + i * 200 + 8 * g;
#pragma unroll
        for (int ks = 0; ks < 6; ++ks) {
#pragma unroll
            for (int a = 0; a < 4; ++a) {
                const bf16x8 av = *(const bf16x8*)(paw + a * 16 * 200 + ks * 32);
                acc[nc * 4 + a][0] = __builtin_amdgcn_mfma_f32_16x16x32_bf16(av, xb[0][ks], acc[nc * 4 + a][0], 0, 0, 0);
                acc[nc * 4 + a][1] = __builtin_amdgcn_mfma_f32_16x16x32_bf16(av, xb[1][ks], acc[nc * 4 + a][1], 0, 0, 0);
            }
        }
        __syncthreads();
    }
#pragma unroll
    for (int tt = 0; tt < 2; ++tt) {
        const int m = m0 + wave * 32 + 16 * tt + i;
        const int t = win_row_to_token(m, shifted);
        const float* xr = xin + (size_t)t * C_DIM;
        float s = 0.0f;
#pragma unroll
        for (int a = 0; a < 12; ++a) {
            const int n0 = 16 * a + 4 * g;
            const float4 xv = *(const float4*)(xr + n0);
            const float4 bi = *(const float4*)(pb + n0);
            acc[a][tt][0] += xv.x + bi.x;
            acc[a][tt][1] += xv.y + bi.y;
            acc[a][tt][2] += xv.z + bi.z;
            acc[a][tt][3] += xv.w + bi.w;
            s += acc[a][tt][0] + acc[a][tt][1] + acc[a][tt][2] + acc[a][tt][3];
        }
        s += __shfl_xor(s, 16, 64);
        s += __shfl_xor(s, 32, 64);
        const float mu = s * (1.0f / 192.0f);
        float sq = 0.0f;
#pragma unroll
        for (int a = 0; a < 12; ++a) {
#pragma unroll
            for (int r = 0; r < 4; ++r) {
                const float d = acc[a][tt][r] - mu;
                sq += d * d;
            }
        }
        sq += __shfl_xor(sq, 16, 64);
        sq += __shfl_xor(sq, 32, 64);
        const float rstd = rsqrtf(sq * (1.0f / 192.0f) + 1e-5f);
        float* x2r = x2 + (size_t)t * C_DIM;
        u16* xnr = x2n + (size_t)t * C_DIM;
#pragma unroll
        for (int a = 0; a < 12; ++a) {
            const int n0 = 16 * a + 4 * g;
            float4 wv;
            wv.x = acc[a][tt][0]; wv.y = acc[a][tt][1];
            wv.z = acc[a][tt][2]; wv.w = acc[a][tt][3];
            *(float4*)(x2r + n0) = wv;
            const float4 gv = *(const float4*)(g2 + n0);
            const float4 bv = *(const float4*)(b2 + n0);
            ushort4 nk;
            nk.x = f2bf((wv.x - mu) * rstd * gv.x + bv.x);
            nk.y = f2bf((wv.y - mu) * rstd * gv.y + bv.y);
            nk.z = f2bf((wv.z - mu) * rstd * gv.z + bv.z);
            nk.w = f2bf((wv.w - mu) * rstd * gv.w + bv.w);
            *(ushort4*)(xnr + n0) = nk;
        }
    }
}

// ---------------------------------------------------------------------------
// FC1 + gelu: weights via DMA; h written in fc2 tile image h_t[nc][m][72].
// ---------------------------------------------------------------------------
__global__ __launch_bounds__(256) void fc1_mfma(const u16* __restrict__ x2n,
                                                const u16* __restrict__ f1wT,
                                                const float* __restrict__ f1b,
                                                u16* __restrict__ h_t) {
    __shared__ __align__(16) u16 Bs[2][64 * 200];
    const int m0 = blockIdx.x * 128;
    const int lane = threadIdx.x & 63, wave = threadIdx.x >> 6;
    const int i = lane & 15, g = lane >> 4;
    stage_wchunk4(f1wT, Bs[0]);
    bf16x8 xb[2][6];
    load_tok_regs(x2n + (size_t)m0 * 192, xb);
    __syncthreads();
#pragma unroll 1
    for (int nc = 0; nc < 12; ++nc) {
        const int cur = nc & 1;
        if (nc < 11) stage_wchunk4(f1wT + (size_t)(nc + 1) * 12800, Bs[cur ^ 1]);
        f32x4 acc[4][2] = {};
        const u16* paw = Bs[cur] + i * 200 + 8 * g;
#pragma unroll
        for (int ks = 0; ks < 6; ++ks) {
#pragma unroll
            for (int a = 0; a < 4; ++a) {
                const bf16x8 av = *(const bf16x8*)(paw + a * 16 * 200 + ks * 32);
                acc[a][0] = __builtin_amdgcn_mfma_f32_16x16x32_bf16(av, xb[0][ks], acc[a][0], 0, 0, 0);
                acc[a][1] = __builtin_amdgcn_mfma_f32_16x16x32_bf16(av, xb[1][ks], acc[a][1], 0, 0, 0);
            }
        }
        u16* hchunk = h_t + (size_t)nc * ((size_t)L_TOK * 72);
#pragma unroll
        for (int a = 0; a < 4; ++a) {
            const int c0 = 16 * a + 4 * g;
            const float4 bi = *(const float4*)(f1b + nc * 64 + c0);
#pragma unroll
            for (int tt = 0; tt < 2; ++tt) {
                const int m = m0 + wave * 32 + 16 * tt + i;
                ushort4 pk;
                pk.x = f2bf(gelu_f(acc[a][tt][0] + bi.x));
                pk.y = f2bf(gelu_f(acc[a][tt][1] + bi.y));
                pk.z = f2bf(gelu_f(acc[a][tt][2] + bi.z));
                pk.w = f2bf(gelu_f(acc[a][tt][3] + bi.w));
                *(ushort4*)(hchunk + (size_t)m * 72 + c0) = pk;
            }
        }
        __syncthreads();
    }
}

// ---------------------------------------------------------------------------
// FC2 + residual (512 threads, M=256): BOTH tiles via global_load_lds.
// ---------------------------------------------------------------------------
__global__ __launch_bounds__(512) void fc2_mfma(const u16* __restrict__ h_t,
                                                const u16* __restrict__ f2wT,
                                                const float* __restrict__ f2b,
                                                const float* x2, float* out) {
    __shared__ __align__(16) u16 As[256 * 72];
    __shared__ __align__(16) u16 Bs[192 * 72];
    const int tid = threadIdx.x, lane = tid & 63, wave = tid >> 6;
    const int i = lane & 15, g = lane >> 4;
    const int m0 = blockIdx.x * 256;
    f32x4 acc[12][2] = {};
#pragma unroll 1
    for (int kc = 0; kc < 12; ++kc) {
        stage_hchunk8(h_t + (size_t)kc * ((size_t)L_TOK * 72) + (size_t)m0 * 72, As);
        stage_wchunk8(f2wT + (size_t)kc * 13824, Bs);
        __syncthreads();
        const u16* pbt = As + (wave * 32 + i) * 72 + 8 * g;
        const u16* paw = Bs + i * 72 + 8 * g;
#pragma unroll
        for (int ks = 0; ks < 2; ++ks) {
            const bf16x8 b0 = *(const bf16x8*)(pbt + ks * 32);
            const bf16x8 b1 = *(const bf16x8*)(pbt + 16 * 72 + ks * 32);
#pragma unroll
            for (int a = 0; a < 12; ++a) {
                const bf16x8 av = *(const bf16x8*)(paw + a * 16 * 72 + ks * 32);
                acc[a][0] = __builtin_amdgcn_mfma_f32_16x16x32_bf16(av, b0, acc[a][0], 0, 0, 0);
                acc[a][1] = __builtin_amdgcn_mfma_f32_16x16x32_bf16(av, b1, acc[a][1], 0, 0, 0);
            }
        }
        __syncthreads();
    }
#pragma unroll
    for (int tt = 0; tt < 2; ++tt) {
        const int m = m0 + wave * 32 + 16 * tt + i;
        const float* x2r = x2 + (size_t)m * C_DIM;
        float* orow = out + (size_t)m * C_DIM;
#pragma unroll
        for (int a = 0; a < 12; ++a) {
            const int n0 = 16 * a + 4 * g;
            const float4 xv = *(const float4*)(x2r + n0);
            const float4 bi = *(const float4*)(f2b + n0);
            float4 rr;
            rr.x = xv.x + bi.x + acc[a][tt][0];
            rr.y = xv.y + bi.y + acc[a][tt][1];
            rr.z = xv.z + bi.z + acc[a][tt][2];
            rr.w = xv.w + bi.w + acc[a][tt][3];
            *(float4*)(orow + n0) = rr;
        }
    }
}

// ---------------------------------------------------------------------------
// orchestration. ws (PB = 48MB): [0,PB) o ; [PB,2PB) q ; [2PB,3PB) k ;
// [3PB,4PB) v ; h_t (12*L*72 u16) overlays [PB, ...); x2n [6PB,7PB) ;
// padded weights at 7PB ; rpbT after. x2 = d_out fp32.
// ---------------------------------------------------------------------------
static void run_block(const float* X, float* XOUT,
                      const float* g1, const float* b1, const float* qb,
                      const float* rpbT, const float* pb,
                      const float* g2, const float* b2,
                      const float* f1b, const float* f2b,
                      const u16* qwT, const u16* pwT, const u16* f1wT, const u16* f2wT,
                      int shifted, char* ws, hipStream_t stream) {
    const size_t PB = (size_t)L_TOK * C_DIM * sizeof(u16);  // 48 MB
    u16* o   = (u16*)ws;
    u16* q   = (u16*)(ws + PB);
    u16* k   = (u16*)(ws + 2 * PB);
    u16* v   = (u16*)(ws + 3 * PB);
    u16* h_t = (u16*)(ws + PB);
    u16* x2n = (u16*)(ws + 6 * PB);
    float* x2 = XOUT;

    qkv_ln_mfma<<<L_TOK / 128, 256, 0, stream>>>(X, g1, b1, qwT, qb, q, k, v, shifted);
    attn_mfma<<<NWIN * 6, 256, 0, stream>>>(q, k, v, rpbT, o, shifted);
    proj_ln_mfma<<<L_TOK / 128, 256, 0, stream>>>(o, pwT, pb, X, g2, b2, x2, x2n, shifted);
    fc1_mfma<<<L_TOK / 128, 256, 0, stream>>>(x2n, f1wT, f1b, h_t);
    fc2_mfma<<<L_TOK / 256, 512, 0, stream>>>(h_t, f2wT, f2b, x2, XOUT);
}

extern "C" void kernel_launch(void* const* d_in, const int* in_sizes, int n_in,
                              void* d_out, int out_size, void* d_ws, size_t ws_size,
                              hipStream_t stream) {
    const float* x = (const float*)d_in[0];
    float* out = (float*)d_out;
    char* ws = (char*)d_ws;
    auto in = [&](int i) { return (const float*)d_in[i]; };

    const size_t offW = (size_t)L_TOK * C_DIM * sizeof(u16) * 7;
    u16* wbase = (u16*)(ws + offW);
    const size_t SQ = 115200, SP = 38400, SF1 = 153600, SF2 = 165888;
    const size_t WBLK = SQ + SP + SF1 + SF2;
    u16* qwT[2]  = { wbase,                    wbase + WBLK };
    u16* pwT[2]  = { wbase + SQ,               wbase + WBLK + SQ };
    u16* f1wT[2] = { wbase + SQ + SP,          wbase + WBLK + SQ + SP };
    u16* f2wT[2] = { wbase + SQ + SP + SF1,    wbase + WBLK + SQ + SP + SF1 };
    float* rpbT0 = (float*)(wbase + 2 * WBLK);
    float* rpbT1 = rpbT0 + 6 * 343;

    WtTable wt;
    wt.s[0] = { in(3),  qwT[0],  576, 576 * 192, 0 };
    wt.s[1] = { in(6),  pwT[0],  192, 192 * 192, 0 };
    wt.s[2] = { in(10), f1wT[0], 768, 768 * 192, 0 };
    wt.s[3] = { in(12), f2wT[0], 192, 192 * 768, 1 };
    wt.s[4] = { in(16), qwT[1],  576, 576 * 192, 0 };
    wt.s[5] = { in(19), pwT[1],  192, 192 * 192, 0 };
    wt.s[6] = { in(23), f1wT[1], 768, 768 * 192, 0 };
    wt.s[7] = { in(25), f2wT[1], 192, 192 * 768, 1 };
    int total = 0;
    for (int s = 0; s < 8; ++s) total += wt.s[s].nelem;
    wtrans_all_kernel<<<(total + 255) / 256, 256, 0, stream>>>(wt);
    rpbt_kernel<<<(343 * 6 + 255) / 256, 256, 0, stream>>>(in(5), in(18), rpbT0, rpbT1);

    run_block(x, out, in(1), in(2), in(4), rpbT0, in(7), in(8), in(9), in(11), in(13),
              qwT[0], pwT[0], f1wT[0], f2wT[0], 0, ws, stream);
    run_block(out, out, in(14), in(15), in(17), rpbT1, in(20), in(21), in(22), in(24), in(26),
              qwT[1], pwT[1], f1wT[1], f2wT[1], 1, ws, stream);
}